// Round 11
// baseline (167.346 us; speedup 1.0000x reference)
//
#include <hip/hip_runtime.h>
#include <cstdint>

#define EPSF 1e-5f
#define SCALEF 0.25f  // D^-0.5

typedef __attribute__((ext_vector_type(8))) __fp16 f16x8;   // 8 fp16 = 4 VGPR
typedef __attribute__((ext_vector_type(2))) __fp16 f16x2;
typedef __attribute__((ext_vector_type(4))) float f32x4;

union U4H8 { uint4 u; f16x8 v; unsigned short s[8]; };

__device__ __forceinline__ uint32_t pk2h(float a, float b){
    union { f16x2 h; uint32_t u; } c;
    c.h = __builtin_amdgcn_cvt_pkrtz(a, b);   // v_cvt_pkrtz_f16_f32
    return c.u;
}
__device__ __forceinline__ void gload_lds16(const void* g, void* l){
    __builtin_amdgcn_global_load_lds((const __attribute__((address_space(1))) uint32_t*)g,
                                     (__attribute__((address_space(3))) uint32_t*)l, 16, 0, 0);
}

// ws layout (bytes):
//   Ft : f16 [64][128 h][256 k]  @ 0          (4,194,304 B)
//   q2 : f32 [256][32][16]       @ 4,194,304  (524,288 B)
//   P  : f32 [256][32][16]       @ 4,718,592  (524,288 B)  -- atomically accumulated

// ---------------------------------------------------------------------------
// Kernel 1: fused weight, transposed + fp16 (unchanged, verified).
// ---------------------------------------------------------------------------
__global__ void k_fuseF(const float* __restrict__ wc, const float* __restrict__ E,
                        unsigned short* __restrict__ Ft){
    const int blk = blockIdx.x;
    const int n2 = blk >> 4, x = blk & 15;
    const int h = threadIdx.x;
    const int j = (n2 & 3) * 16 + x;
    float w[16];
#pragma unroll
    for (int t = 0; t < 16; ++t) w[t] = wc[j * 16 + t];
    const float* Eb = E + ((size_t)n2 * 256 + x * 16) * 128 + h;
    float e[16];
#pragma unroll
    for (int t = 0; t < 16; ++t) e[t] = Eb[(size_t)t * 128];
    float v[16];
#pragma unroll
    for (int dd = 0; dd < 16; ++dd){
        const int r = dd >> 2, k = dd & 3;
        float acc = 0.f;
#pragma unroll
        for (int c = 0; c < 4; ++c) acc += w[k * 4 + c] * e[r * 4 + c];
        v[dd] = acc;
    }
    uint32_t pk[8];
#pragma unroll
    for (int q = 0; q < 8; ++q) pk[q] = pk2h(v[q * 2], v[q * 2 + 1]);
    unsigned short* dst = Ft + (size_t)n2 * 32768 + (size_t)h * 256 + x * 16;
    ((uint4*)dst)[0] = make_uint4(pk[0], pk[1], pk[2], pk[3]);
    ((uint4*)dst)[1] = make_uint4(pk[4], pk[5], pk[6], pk[7]);
}

// ---------------------------------------------------------------------------
// Kernel 2: q2 (unchanged, verified).
// ---------------------------------------------------------------------------
__global__ void k_q2(const float* __restrict__ npse, const float* __restrict__ wn,
                     float* __restrict__ q2g){
    const int b = blockIdx.x;
    const int t = threadIdx.x;           // 0..511
    const int o = t >> 4, d = t & 15, r = d >> 2, c = d & 3;
    float acc = 0.f;
#pragma unroll
    for (int k = 0; k < 4; ++k)
        acc += wn[o * 16 + r * 4 + k] * npse[((size_t)b * 32 + o) * 16 + k * 4 + c];
    q2g[(size_t)b * 512 + t] = acc * SCALEF;
}

// ---------------------------------------------------------------------------
// Kernel 3: FUSED GEMM + routing. Main loop = exact r4 gemm (verified).
// Epilogue (replaces kv global write): per wave (wm = batch-half, wn2 = n-half),
// per b (mf): logits via mfma(A=q2 slots {8g+i -> e=4g+i, i<4}, B=C-frag
// direct with slots 4..7 zeroed); softmax per n (in-lane 8 + shfl 16,32);
// kvT/wJ swizzled staging (r10-verified formulas); PV 2xK=32 MFMAs;
// atomicAdd partials into P[b][32][16].
// ---------------------------------------------------------------------------
__global__ __launch_bounds__(256, 4) void k_gemm(const float* __restrict__ cp,
                                                 const unsigned short* __restrict__ Ft,
                                                 const float* __restrict__ q2g,
                                                 float* __restrict__ P){
    __shared__ __align__(16) char smem[32768];
    unsigned short (*As)[4096] = (unsigned short (*)[4096])smem;           // 2 x 8 KB
    unsigned short (*Fs)[4096] = (unsigned short (*)[4096])(smem + 16384); // 2 x 8 KB
    const int tid  = threadIdx.x;
    const int lane = tid & 63;
    const int wave = tid >> 6;              // 0..3
    const int wm = wave >> 1, wn2 = wave & 1;
    const int l15 = lane & 15, g = lane >> 4;
    const int mtile = blockIdx.x;           // 0..31
    const int n2 = blockIdx.y;              // 0..63
    const int n2h = n2 >> 4, y = n2 & 15;

    const float* abase[4];
    int aoff[4];
#pragma unroll
    for (int p = 0; p < 4; ++p){
        const int idx = tid + p * 256;      // 0..1023
        const int m = idx >> 3;             // 0..127
        const int kq = idx & 7;             // k = kq*4
        const int b = mtile * 8 + (m >> 4);
        const int i = (m & 15) * 4 + n2h;
        abase[p] = cp + (size_t)b * 262144 + (size_t)i * 4096 + (size_t)y * 256 + kq * 4;
        aoff[p] = m * 32 + (((kq >> 1) ^ ((m >> 1) & 3)) * 8) + (kq & 1) * 4;
    }
    const unsigned short* bsrc[2];
    unsigned short* bdst[2];                // wave-uniform LDS base (lane x16B auto)
#pragma unroll
    for (int p = 0; p < 2; ++p){
        const int idx = tid + p * 256;      // 0..511
        const int h = idx >> 2;             // 0..127
        const int kq4 = idx & 3;            // chunk of 8 f16
        bsrc[p] = Ft + (size_t)n2 * 32768 + (size_t)h * 256 + ((kq4 ^ ((h >> 1) & 3)) * 8);
        bdst[p] = &Fs[0][(size_t)(p * 256 + (tid & ~63)) * 8];
    }
    int afoff[4], bfoff[4];
#pragma unroll
    for (int mf = 0; mf < 4; ++mf){
        const int row = wm * 64 + mf * 16 + l15;
        afoff[mf] = row * 32 + ((g ^ ((row >> 1) & 3)) * 8);
    }
#pragma unroll
    for (int nf = 0; nf < 4; ++nf){
        const int row = wn2 * 64 + nf * 16 + l15;
        bfoff[nf] = row * 32 + ((g ^ ((row >> 1) & 3)) * 8);
    }

    f32x4 acc[4][4];
#pragma unroll
    for (int mf = 0; mf < 4; ++mf)
#pragma unroll
        for (int nf = 0; nf < 4; ++nf) acc[mf][nf] = (f32x4){0.f, 0.f, 0.f, 0.f};

    float4 av[4];
    const int FBUF = 128 * 32;   // ushorts per Fs buffer
#pragma unroll
    for (int p = 0; p < 4; ++p) av[p] = *(const float4*)(abase[p]);
#pragma unroll
    for (int p = 0; p < 2; ++p) gload_lds16(bsrc[p], bdst[p]);
#pragma unroll
    for (int p = 0; p < 4; ++p){
        uint2 w2 = make_uint2(pk2h(av[p].x, av[p].y), pk2h(av[p].z, av[p].w));
        *(uint2*)(&As[0][aoff[p]]) = w2;
    }
    __syncthreads();

    for (int kt = 0; kt < 8; ++kt){
        const int cur = kt & 1;
        if (kt < 7){
#pragma unroll
            for (int p = 0; p < 4; ++p) av[p] = *(const float4*)(abase[p] + (kt + 1) * 32);
#pragma unroll
            for (int p = 0; p < 2; ++p)
                gload_lds16(bsrc[p] + (kt + 1) * 32, bdst[p] + (cur ^ 1) * FBUF);
        }
        f16x8 af[4], bfr[4];
#pragma unroll
        for (int mf = 0; mf < 4; ++mf) af[mf] = *(const f16x8*)(&As[cur][afoff[mf]]);
#pragma unroll
        for (int nf = 0; nf < 4; ++nf) bfr[nf] = *(const f16x8*)(&Fs[cur][bfoff[nf]]);
#pragma unroll
        for (int nf = 0; nf < 4; ++nf)
#pragma unroll
            for (int mf = 0; mf < 4; ++mf)
                acc[mf][nf] = __builtin_amdgcn_mfma_f32_16x16x32_f16(af[mf], bfr[nf], acc[mf][nf], 0, 0, 0);
        if (kt < 7){
            const int nxt = cur ^ 1;
#pragma unroll
            for (int p = 0; p < 4; ++p){
                uint2 w2 = make_uint2(pk2h(av[p].x, av[p].y), pk2h(av[p].z, av[p].w));
                *(uint2*)(&As[nxt][aoff[p]]) = w2;
            }
        }
        __syncthreads();
    }
    // All As/Fs consumption done (each wave's ds_reads retired before its last
    // barrier) -> epilogue may alias smem. Per-wave private 6 KB slices.

    char* eb  = smem + wave * 6144;
    char* kvT = eb;            // [16 e][128 B] col n*2 ^ ((e&7)<<4)
    char* wJ  = eb + 2048;     // [32 j][128 B] col n*2 ^ ((j&7)<<4)
    const f32x4 zf = (f32x4){0.f, 0.f, 0.f, 0.f};

    for (int mf = 0; mf < 4; ++mf){
        const int b = mtile * 8 + wm * 4 + mf;
        // q2 A-frags: lane l15 = j-row; slot 8g+i -> e = 4g+i (i<4), 0 (i>=4)
        U4H8 aq[2];
#pragma unroll
        for (int jh = 0; jh < 2; ++jh){
            const float4 q = *(const float4*)(q2g + (size_t)b * 512
                                              + (size_t)(jh * 16 + l15) * 16 + g * 4);
            aq[jh].u = make_uint4(pk2h(q.x, q.y), pk2h(q.z, q.w), 0u, 0u);
        }
        f32x4 pv0 = zf, pv1 = zf;
#pragma unroll
        for (int nf = 0; nf < 4; ++nf){
            // B-frag direct from C-frag: lane l15 = n-col; slots 0..3 = e 4g+r
            U4H8 B;
            B.u = make_uint4(pk2h(acc[mf][nf][0], acc[mf][nf][1]),
                             pk2h(acc[mf][nf][2], acc[mf][nf][3]), 0u, 0u);
            const int ncol2 = (nf * 16 + l15) * 2;
            // kvT writes (same fp16 values feed logits and PV)
#pragma unroll
            for (int r = 0; r < 4; ++r){
                const int e = g * 4 + r;
                *(unsigned short*)(kvT + e * 128 + (ncol2 ^ ((e & 7) << 4))) = B.s[r];
            }
            f32x4 s0 = __builtin_amdgcn_mfma_f32_16x16x32_f16(aq[0].v, B.v, zf, 0, 0, 0);
            f32x4 s1 = __builtin_amdgcn_mfma_f32_16x16x32_f16(aq[1].v, B.v, zf, 0, 0, 0);
            float e0[4], e1[4];
#pragma unroll
            for (int r = 0; r < 4; ++r){ e0[r] = __expf(s0[r]); e1[r] = __expf(s1[r]); }
            float ts = ((e0[0] + e0[1]) + (e0[2] + e0[3]))
                     + ((e1[0] + e1[1]) + (e1[2] + e1[3]));
            ts += __shfl_xor(ts, 16);
            ts += __shfl_xor(ts, 32);
            const float dinv = 1.f / ts;
#pragma unroll
            for (int r = 0; r < 4; ++r){
                const int j0 = 4 * g + r;
                const int sw = (j0 & 7) << 4;           // (16+j0)&7 == j0&7
                *(unsigned short*)(wJ + j0 * 128 + (ncol2 ^ sw)) =
                    (unsigned short)(pk2h(e0[r] * dinv, 0.f) & 0xFFFFu);
                *(unsigned short*)(wJ + (16 + j0) * 128 + (ncol2 ^ sw)) =
                    (unsigned short)(pk2h(e1[r] * dinv, 0.f) & 0xFFFFu);
            }
        }
        // PV: cand[j][e] += sum_n w[j][n] kv[n][e] over this wave's 64 n
#pragma unroll
        for (int kb = 0; kb < 2; ++kb){
            const int cb = kb * 64 + g * 16;
            const int swl = (l15 & 7) << 4;
            U4H8 A0, A1, Bv;
            A0.u = *(const uint4*)(wJ + l15 * 128 + (cb ^ swl));
            A1.u = *(const uint4*)(wJ + (16 + l15) * 128 + (cb ^ swl));
            Bv.u = *(const uint4*)(kvT + l15 * 128 + (cb ^ swl));
            pv0 = __builtin_amdgcn_mfma_f32_16x16x32_f16(A0.v, Bv.v, pv0, 0, 0, 0);
            pv1 = __builtin_amdgcn_mfma_f32_16x16x32_f16(A1.v, Bv.v, pv1, 0, 0, 0);
        }
        // accumulate partial into P[b][j][e]  (D_pv: col l15 = e, row j = 4g+r)
        float* Pb = P + (size_t)b * 512;
#pragma unroll
        for (int r = 0; r < 4; ++r){
            atomicAdd(Pb + ((4 * g + r) * 16) + l15, pv0[r]);
            atomicAdd(Pb + ((16 + 4 * g + r) * 16) + l15, pv1[r]);
        }
    }
}

// ---------------------------------------------------------------------------
// Kernel 4: w_next transform + LayerNorm from the atomically-summed P.
// ---------------------------------------------------------------------------
__global__ __launch_bounds__(512) void k_fin(const float* __restrict__ P,
                                             const float* __restrict__ wn,
                                             const float* __restrict__ lnw,
                                             const float* __restrict__ lnb,
                                             float* __restrict__ out){
    __shared__ float cnd[512];
    const int b = blockIdx.x, t = threadIdx.x;
    cnd[t] = P[(size_t)b * 512 + t];
    __syncthreads();
    if (t < 32){
        const int o = t;
        float m2[16];
#pragma unroll
        for (int r = 0; r < 4; ++r)
#pragma unroll
            for (int c = 0; c < 4; ++c){
                float a = 0.f;
#pragma unroll
                for (int k = 0; k < 4; ++k)
                    a += wn[o * 16 + r * 4 + k] * cnd[o * 16 + k * 4 + c];
                m2[r * 4 + c] = a;
            }
        float mu = 0.f;
#pragma unroll
        for (int e = 0; e < 16; ++e) mu += m2[e];
        mu *= (1.f / 16.f);
        float var = 0.f;
#pragma unroll
        for (int e = 0; e < 16; ++e){ const float d = m2[e] - mu; var += d * d; }
        var *= (1.f / 16.f);
        const float invs = rsqrtf(var + EPSF);
#pragma unroll
        for (int e = 0; e < 16; ++e)
            out[(size_t)b * 512 + o * 16 + e] = (m2[e] - mu) * invs * lnw[e] + lnb[e];
    }
}

// ---------------------------------------------------------------------------
extern "C" void kernel_launch(void* const* d_in, const int* in_sizes, int n_in,
                              void* d_out, int out_size, void* d_ws, size_t ws_size,
                              hipStream_t stream){
    const float* cp   = (const float*)d_in[0];   // current_pose [256][64][16][16][16]
    const float* npse = (const float*)d_in[1];   // next_pose    [256][32][16]
    const float* wc   = (const float*)d_in[2];   // w_current    [64][4][4]
    const float* wn   = (const float*)d_in[3];   // w_next       [32][4][4]
    const float* E    = (const float*)d_in[4];   // E_proj       [64][256][128]
    const float* lnw  = (const float*)d_in[5];   // ln_weight    [16]
    const float* lnb  = (const float*)d_in[6];   // ln_bias      [16]
    float* out = (float*)d_out;

    char* ws = (char*)d_ws;
    unsigned short* Ft  = (unsigned short*)ws;                 // 4,194,304 B
    float*          q2g = (float*)(ws + 4194304);              // 524,288 B
    float*          Pp  = (float*)(ws + 4718592);              // 524,288 B

    hipMemsetAsync(Pp, 0, 524288, stream);   // zero accumulator (graph-capturable)
    hipLaunchKernelGGL(k_fuseF, dim3(1024), dim3(128), 0, stream, wc, E, Ft);
    hipLaunchKernelGGL(k_q2,    dim3(256),  dim3(512), 0, stream, npse, wn, q2g);
    hipLaunchKernelGGL(k_gemm,  dim3(32, 64), dim3(256), 0, stream, cp, Ft, q2g, Pp);
    hipLaunchKernelGGL(k_fin,   dim3(256),  dim3(512), 0, stream, Pp, wn, lnw, lnb, out);
}

// Round 12
// 96.552 us; speedup vs baseline: 1.7332x; 1.7332x over previous
//
#include <hip/hip_runtime.h>
#include <cstdint>

#define EPSF 1e-5f
#define SCALEF 0.25f  // D^-0.5

typedef __attribute__((ext_vector_type(8))) __fp16 f16x8;   // 8 fp16 = 4 VGPR
typedef __attribute__((ext_vector_type(2))) __fp16 f16x2;
typedef __attribute__((ext_vector_type(4))) float f32x4;

union U4H8 { uint4 u; f16x8 v; unsigned short s[8]; };

__device__ __forceinline__ uint32_t pk2h(float a, float b){
    union { f16x2 h; uint32_t u; } c;
    c.h = __builtin_amdgcn_cvt_pkrtz(a, b);   // v_cvt_pkrtz_f16_f32
    return c.u;
}
__device__ __forceinline__ void gload_lds16(const void* g, void* l){
    __builtin_amdgcn_global_load_lds((const __attribute__((address_space(1))) uint32_t*)g,
                                     (__attribute__((address_space(3))) uint32_t*)l, 16, 0, 0);
}

// ws layout (bytes):
//   Ft   : f16 [64][128 h][256 k]   @ 0          (4,194,304 B)
//   q2   : f32 [256][32][16]        @ 4,194,304  (524,288 B)
//   Pmid : f32 [64 n2][256 b][512]  @ 4,718,592  (33,554,432 B)

// ---------------------------------------------------------------------------
// Kernel 1: fused weight, transposed + fp16 (unchanged, verified).
// ---------------------------------------------------------------------------
__global__ void k_fuseF(const float* __restrict__ wc, const float* __restrict__ E,
                        unsigned short* __restrict__ Ft){
    const int blk = blockIdx.x;
    const int n2 = blk >> 4, x = blk & 15;
    const int h = threadIdx.x;
    const int j = (n2 & 3) * 16 + x;
    float w[16];
#pragma unroll
    for (int t = 0; t < 16; ++t) w[t] = wc[j * 16 + t];
    const float* Eb = E + ((size_t)n2 * 256 + x * 16) * 128 + h;
    float e[16];
#pragma unroll
    for (int t = 0; t < 16; ++t) e[t] = Eb[(size_t)t * 128];
    float v[16];
#pragma unroll
    for (int dd = 0; dd < 16; ++dd){
        const int r = dd >> 2, k = dd & 3;
        float acc = 0.f;
#pragma unroll
        for (int c = 0; c < 4; ++c) acc += w[k * 4 + c] * e[r * 4 + c];
        v[dd] = acc;
    }
    uint32_t pk[8];
#pragma unroll
    for (int q = 0; q < 8; ++q) pk[q] = pk2h(v[q * 2], v[q * 2 + 1]);
    unsigned short* dst = Ft + (size_t)n2 * 32768 + (size_t)h * 256 + x * 16;
    ((uint4*)dst)[0] = make_uint4(pk[0], pk[1], pk[2], pk[3]);
    ((uint4*)dst)[1] = make_uint4(pk[4], pk[5], pk[6], pk[7]);
}

// ---------------------------------------------------------------------------
// Kernel 2: q2 (unchanged, verified).
// ---------------------------------------------------------------------------
__global__ void k_q2(const float* __restrict__ npse, const float* __restrict__ wn,
                     float* __restrict__ q2g){
    const int b = blockIdx.x;
    const int t = threadIdx.x;           // 0..511
    const int o = t >> 4, d = t & 15, r = d >> 2, c = d & 3;
    float acc = 0.f;
#pragma unroll
    for (int k = 0; k < 4; ++k)
        acc += wn[o * 16 + r * 4 + k] * npse[((size_t)b * 32 + o) * 16 + k * 4 + c];
    q2g[(size_t)b * 512 + t] = acc * SCALEF;
}

// ---------------------------------------------------------------------------
// Kernel 3: FUSED GEMM + routing (r11 semantics, codegen fixed):
//  - epilogue mf loop now FULLY UNROLLED (rule #20: runtime-indexed acc was
//    demoted to scratch -> 262 MB spill traffic, the r11 regression)
//  - atomics replaced by cross-wave LDS pair-reduce + regular stores into
//    Pmid[n2][b][512]; k_fin sums the 64 n2 slices.
// ---------------------------------------------------------------------------
__global__ __launch_bounds__(256, 4) void k_gemm(const float* __restrict__ cp,
                                                 const unsigned short* __restrict__ Ft,
                                                 const float* __restrict__ q2g,
                                                 float* __restrict__ Pmid){
    __shared__ __align__(16) char smem[32768];
    unsigned short (*As)[4096] = (unsigned short (*)[4096])smem;           // 2 x 8 KB
    unsigned short (*Fs)[4096] = (unsigned short (*)[4096])(smem + 16384); // 2 x 8 KB
    const int tid  = threadIdx.x;
    const int lane = tid & 63;
    const int wave = tid >> 6;              // 0..3
    const int wm = wave >> 1, wn2 = wave & 1;
    const int l15 = lane & 15, g = lane >> 4;
    const int mtile = blockIdx.x;           // 0..31
    const int n2 = blockIdx.y;              // 0..63
    const int n2h = n2 >> 4, y = n2 & 15;

    const float* abase[4];
    int aoff[4];
#pragma unroll
    for (int p = 0; p < 4; ++p){
        const int idx = tid + p * 256;      // 0..1023
        const int m = idx >> 3;             // 0..127
        const int kq = idx & 7;             // k = kq*4
        const int b = mtile * 8 + (m >> 4);
        const int i = (m & 15) * 4 + n2h;
        abase[p] = cp + (size_t)b * 262144 + (size_t)i * 4096 + (size_t)y * 256 + kq * 4;
        aoff[p] = m * 32 + (((kq >> 1) ^ ((m >> 1) & 3)) * 8) + (kq & 1) * 4;
    }
    const unsigned short* bsrc[2];
    unsigned short* bdst[2];                // wave-uniform LDS base (lane x16B auto)
#pragma unroll
    for (int p = 0; p < 2; ++p){
        const int idx = tid + p * 256;      // 0..511
        const int h = idx >> 2;             // 0..127
        const int kq4 = idx & 3;            // chunk of 8 f16
        bsrc[p] = Ft + (size_t)n2 * 32768 + (size_t)h * 256 + ((kq4 ^ ((h >> 1) & 3)) * 8);
        bdst[p] = &Fs[0][(size_t)(p * 256 + (tid & ~63)) * 8];
    }
    int afoff[4], bfoff[4];
#pragma unroll
    for (int mf = 0; mf < 4; ++mf){
        const int row = wm * 64 + mf * 16 + l15;
        afoff[mf] = row * 32 + ((g ^ ((row >> 1) & 3)) * 8);
    }
#pragma unroll
    for (int nf = 0; nf < 4; ++nf){
        const int row = wn2 * 64 + nf * 16 + l15;
        bfoff[nf] = row * 32 + ((g ^ ((row >> 1) & 3)) * 8);
    }

    f32x4 acc[4][4];
#pragma unroll
    for (int mf = 0; mf < 4; ++mf)
#pragma unroll
        for (int nf = 0; nf < 4; ++nf) acc[mf][nf] = (f32x4){0.f, 0.f, 0.f, 0.f};

    float4 av[4];
    const int FBUF = 128 * 32;   // ushorts per Fs buffer
#pragma unroll
    for (int p = 0; p < 4; ++p) av[p] = *(const float4*)(abase[p]);
#pragma unroll
    for (int p = 0; p < 2; ++p) gload_lds16(bsrc[p], bdst[p]);
#pragma unroll
    for (int p = 0; p < 4; ++p){
        uint2 w2 = make_uint2(pk2h(av[p].x, av[p].y), pk2h(av[p].z, av[p].w));
        *(uint2*)(&As[0][aoff[p]]) = w2;
    }
    __syncthreads();

    for (int kt = 0; kt < 8; ++kt){
        const int cur = kt & 1;
        if (kt < 7){
#pragma unroll
            for (int p = 0; p < 4; ++p) av[p] = *(const float4*)(abase[p] + (kt + 1) * 32);
#pragma unroll
            for (int p = 0; p < 2; ++p)
                gload_lds16(bsrc[p] + (kt + 1) * 32, bdst[p] + (cur ^ 1) * FBUF);
        }
        f16x8 af[4], bfr[4];
#pragma unroll
        for (int mf = 0; mf < 4; ++mf) af[mf] = *(const f16x8*)(&As[cur][afoff[mf]]);
#pragma unroll
        for (int nf = 0; nf < 4; ++nf) bfr[nf] = *(const f16x8*)(&Fs[cur][bfoff[nf]]);
#pragma unroll
        for (int nf = 0; nf < 4; ++nf)
#pragma unroll
            for (int mf = 0; mf < 4; ++mf)
                acc[mf][nf] = __builtin_amdgcn_mfma_f32_16x16x32_f16(af[mf], bfr[nf], acc[mf][nf], 0, 0, 0);
        if (kt < 7){
            const int nxt = cur ^ 1;
#pragma unroll
            for (int p = 0; p < 4; ++p){
                uint2 w2 = make_uint2(pk2h(av[p].x, av[p].y), pk2h(av[p].z, av[p].w));
                *(uint2*)(&As[nxt][aoff[p]]) = w2;
            }
        }
        __syncthreads();
    }
    // Past the last barrier: all LDS reads retired; epilogue aliases smem.
    // Per-wave private 6 KB slices.

    char* eb  = smem + wave * 6144;
    char* kvT = eb;            // [16 e][128 B] col n*2 ^ ((e&7)<<4)
    char* wJ  = eb + 2048;     // [32 j][128 B] col n*2 ^ ((j&7)<<4)
    const f32x4 zf = (f32x4){0.f, 0.f, 0.f, 0.f};
    f32x4 pvm[4][2];

#pragma unroll
    for (int mf = 0; mf < 4; ++mf){
        const int b = mtile * 8 + wm * 4 + mf;
        // q2 A-frags: lane l15 = j-row; slot 8g+i -> e = 4g+i (i<4), 0 (i>=4)
        U4H8 aq[2];
#pragma unroll
        for (int jh = 0; jh < 2; ++jh){
            const float4 q = *(const float4*)(q2g + (size_t)b * 512
                                              + (size_t)(jh * 16 + l15) * 16 + g * 4);
            aq[jh].u = make_uint4(pk2h(q.x, q.y), pk2h(q.z, q.w), 0u, 0u);
        }
        f32x4 pv0 = zf, pv1 = zf;
#pragma unroll
        for (int nf = 0; nf < 4; ++nf){
            // B-frag direct from C-frag: lane l15 = n-col; slots 0..3 = e 4g+r
            U4H8 B;
            B.u = make_uint4(pk2h(acc[mf][nf][0], acc[mf][nf][1]),
                             pk2h(acc[mf][nf][2], acc[mf][nf][3]), 0u, 0u);
            const int ncol2 = (nf * 16 + l15) * 2;
#pragma unroll
            for (int r = 0; r < 4; ++r){
                const int e = g * 4 + r;
                *(unsigned short*)(kvT + e * 128 + (ncol2 ^ ((e & 7) << 4))) = B.s[r];
            }
            f32x4 s0 = __builtin_amdgcn_mfma_f32_16x16x32_f16(aq[0].v, B.v, zf, 0, 0, 0);
            f32x4 s1 = __builtin_amdgcn_mfma_f32_16x16x32_f16(aq[1].v, B.v, zf, 0, 0, 0);
            float e0[4], e1[4];
#pragma unroll
            for (int r = 0; r < 4; ++r){ e0[r] = __expf(s0[r]); e1[r] = __expf(s1[r]); }
            float ts = ((e0[0] + e0[1]) + (e0[2] + e0[3]))
                     + ((e1[0] + e1[1]) + (e1[2] + e1[3]));
            ts += __shfl_xor(ts, 16);
            ts += __shfl_xor(ts, 32);
            const float dinv = 1.f / ts;
#pragma unroll
            for (int r = 0; r < 4; ++r){
                const int j0 = 4 * g + r;
                const int sw = (j0 & 7) << 4;           // (16+j0)&7 == j0&7
                *(unsigned short*)(wJ + j0 * 128 + (ncol2 ^ sw)) =
                    (unsigned short)(pk2h(e0[r] * dinv, 0.f) & 0xFFFFu);
                *(unsigned short*)(wJ + (16 + j0) * 128 + (ncol2 ^ sw)) =
                    (unsigned short)(pk2h(e1[r] * dinv, 0.f) & 0xFFFFu);
            }
        }
        // PV: cand[j][e] += sum_n w[j][n] kv[n][e] over this wave's 64 n
#pragma unroll
        for (int kb = 0; kb < 2; ++kb){
            const int cb = kb * 64 + g * 16;
            const int swl = (l15 & 7) << 4;
            U4H8 A0, A1, Bv;
            A0.u = *(const uint4*)(wJ + l15 * 128 + (cb ^ swl));
            A1.u = *(const uint4*)(wJ + (16 + l15) * 128 + (cb ^ swl));
            Bv.u = *(const uint4*)(kvT + l15 * 128 + (cb ^ swl));
            pv0 = __builtin_amdgcn_mfma_f32_16x16x32_f16(A0.v, Bv.v, pv0, 0, 0, 0);
            pv1 = __builtin_amdgcn_mfma_f32_16x16x32_f16(A1.v, Bv.v, pv1, 0, 0, 0);
        }
        pvm[mf][0] = pv0;
        pvm[mf][1] = pv1;
    }

    // ---- cross-wave pair reduce (wn2=0 + wn2=1 share the same 4 b's) ----
    __syncthreads();
    float* pvbuf = (float*)(smem + wm * 8192);   // [4 mf][32 j][16 e] f32
    if (wn2 == 0){
#pragma unroll
        for (int mf = 0; mf < 4; ++mf)
#pragma unroll
            for (int jh = 0; jh < 2; ++jh)
#pragma unroll
                for (int r = 0; r < 4; ++r)
                    pvbuf[mf * 512 + (jh * 16 + 4 * g + r) * 16 + l15] = pvm[mf][jh][r];
    }
    __syncthreads();
    if (wn2 == 1){
#pragma unroll
        for (int mf = 0; mf < 4; ++mf){
            const int b = mtile * 8 + wm * 4 + mf;
            float* dst = Pmid + (size_t)n2 * 131072 + (size_t)b * 512;
#pragma unroll
            for (int jh = 0; jh < 2; ++jh)
#pragma unroll
                for (int r = 0; r < 4; ++r){
                    const int idx = (jh * 16 + 4 * g + r) * 16 + l15;
                    dst[idx] = pvbuf[mf * 512 + idx] + pvm[mf][jh][r];
                }
        }
    }
}

// ---------------------------------------------------------------------------
// Kernel 4: sum 64 n2 slices, w_next transform, LayerNorm, store.
// ---------------------------------------------------------------------------
__global__ __launch_bounds__(512) void k_fin(const float* __restrict__ Pmid,
                                             const float* __restrict__ wn,
                                             const float* __restrict__ lnw,
                                             const float* __restrict__ lnb,
                                             float* __restrict__ out){
    __shared__ float cnd[512];
    const int b = blockIdx.x, t = threadIdx.x;
    float s = 0.f;
#pragma unroll 8
    for (int n2 = 0; n2 < 64; ++n2)
        s += Pmid[(size_t)n2 * 131072 + (size_t)b * 512 + t];
    cnd[t] = s;
    __syncthreads();
    if (t < 32){
        const int o = t;
        float m2[16];
#pragma unroll
        for (int r = 0; r < 4; ++r)
#pragma unroll
            for (int c = 0; c < 4; ++c){
                float a = 0.f;
#pragma unroll
                for (int k = 0; k < 4; ++k)
                    a += wn[o * 16 + r * 4 + k] * cnd[o * 16 + k * 4 + c];
                m2[r * 4 + c] = a;
            }
        float mu = 0.f;
#pragma unroll
        for (int e = 0; e < 16; ++e) mu += m2[e];
        mu *= (1.f / 16.f);
        float var = 0.f;
#pragma unroll
        for (int e = 0; e < 16; ++e){ const float d = m2[e] - mu; var += d * d; }
        var *= (1.f / 16.f);
        const float invs = rsqrtf(var + EPSF);
#pragma unroll
        for (int e = 0; e < 16; ++e)
            out[(size_t)b * 512 + o * 16 + e] = (m2[e] - mu) * invs * lnw[e] + lnb[e];
    }
}

// ---------------------------------------------------------------------------
extern "C" void kernel_launch(void* const* d_in, const int* in_sizes, int n_in,
                              void* d_out, int out_size, void* d_ws, size_t ws_size,
                              hipStream_t stream){
    const float* cp   = (const float*)d_in[0];   // current_pose [256][64][16][16][16]
    const float* npse = (const float*)d_in[1];   // next_pose    [256][32][16]
    const float* wc   = (const float*)d_in[2];   // w_current    [64][4][4]
    const float* wn   = (const float*)d_in[3];   // w_next       [32][4][4]
    const float* E    = (const float*)d_in[4];   // E_proj       [64][256][128]
    const float* lnw  = (const float*)d_in[5];   // ln_weight    [16]
    const float* lnb  = (const float*)d_in[6];   // ln_bias      [16]
    float* out = (float*)d_out;

    char* ws = (char*)d_ws;
    unsigned short* Ft   = (unsigned short*)ws;                // 4,194,304 B
    float*          q2g  = (float*)(ws + 4194304);             // 524,288 B
    float*          Pmid = (float*)(ws + 4718592);             // 33,554,432 B

    hipLaunchKernelGGL(k_fuseF, dim3(1024), dim3(128), 0, stream, wc, E, Ft);
    hipLaunchKernelGGL(k_q2,    dim3(256),  dim3(512), 0, stream, npse, wn, q2g);
    hipLaunchKernelGGL(k_gemm,  dim3(32, 64), dim3(256), 0, stream, cp, Ft, q2g, Pmid);
    hipLaunchKernelGGL(k_fin,   dim3(256),  dim3(512), 0, stream, Pmid, wn, lnw, lnb, out);
}

// Round 13
// 81.492 us; speedup vs baseline: 2.0535x; 1.1848x over previous
//
#include <hip/hip_runtime.h>
#include <cstdint>

#define EPSF 1e-5f
#define SCALEF 0.25f  // D^-0.5

typedef __attribute__((ext_vector_type(8))) __fp16 f16x8;   // 8 fp16 = 4 VGPR
typedef __attribute__((ext_vector_type(2))) __fp16 f16x2;
typedef __attribute__((ext_vector_type(4))) float f32x4;

union U4H8 { uint4 u; f16x8 v; unsigned short s[8]; };
union U1H2 { unsigned u; f16x2 h; };

__device__ __forceinline__ uint32_t pk2h(float a, float b){
    union { f16x2 h; uint32_t u; } c;
    c.h = __builtin_amdgcn_cvt_pkrtz(a, b);   // v_cvt_pkrtz_f16_f32
    return c.u;
}
__device__ __forceinline__ void gload_lds16(const void* g, void* l){
    __builtin_amdgcn_global_load_lds((const __attribute__((address_space(1))) uint32_t*)g,
                                     (__attribute__((address_space(3))) uint32_t*)l, 16, 0, 0);
}

// ws layout (bytes):
//   Ft   : f16 [64][128 h][256 k]   @ 0          (4,194,304 B)
//   q2   : f32 [256][32][16]        @ 4,194,304  (524,288 B)
//   Pmid : f16 [64 n2][256 b][512]  @ 4,718,592  (16,777,216 B)

// ---------------------------------------------------------------------------
// Kernel 1: merged init. blocks 0..1023: fuseF (verified math); 1024..1279: q2.
// 128 threads.
// ---------------------------------------------------------------------------
__global__ void k_init(const float* __restrict__ wc, const float* __restrict__ E,
                       const float* __restrict__ npse, const float* __restrict__ wnx,
                       unsigned short* __restrict__ Ft, float* __restrict__ q2g){
    const int blk = blockIdx.x;
    const int tid = threadIdx.x;
    if (blk < 1024){
        const int n2 = blk >> 4, x = blk & 15;
        const int h = tid;
        const int j = (n2 & 3) * 16 + x;
        float w[16];
#pragma unroll
        for (int t = 0; t < 16; ++t) w[t] = wc[j * 16 + t];
        const float* Eb = E + ((size_t)n2 * 256 + x * 16) * 128 + h;
        float e[16];
#pragma unroll
        for (int t = 0; t < 16; ++t) e[t] = Eb[(size_t)t * 128];
        float v[16];
#pragma unroll
        for (int dd = 0; dd < 16; ++dd){
            const int r = dd >> 2, k = dd & 3;
            float acc = 0.f;
#pragma unroll
            for (int c = 0; c < 4; ++c) acc += w[k * 4 + c] * e[r * 4 + c];
            v[dd] = acc;
        }
        uint32_t pk[8];
#pragma unroll
        for (int q = 0; q < 8; ++q) pk[q] = pk2h(v[q * 2], v[q * 2 + 1]);
        unsigned short* dst = Ft + (size_t)n2 * 32768 + (size_t)h * 256 + x * 16;
        ((uint4*)dst)[0] = make_uint4(pk[0], pk[1], pk[2], pk[3]);
        ((uint4*)dst)[1] = make_uint4(pk[4], pk[5], pk[6], pk[7]);
    } else {
        const int b = blk - 1024;
#pragma unroll
        for (int q = 0; q < 4; ++q){
            const int t = q * 128 + tid;     // 0..511
            const int o = t >> 4, d = t & 15, r = d >> 2, c = d & 3;
            float acc = 0.f;
#pragma unroll
            for (int k = 0; k < 4; ++k)
                acc += wnx[o * 16 + r * 4 + k] * npse[((size_t)b * 32 + o) * 16 + k * 4 + c];
            q2g[(size_t)b * 512 + t] = acc * SCALEF;
        }
    }
}

// ---------------------------------------------------------------------------
// Kernel 2: FUSED GEMM + routing, counted-vmcnt 3-buffer B pipeline.
// Invariant (full unroll): entering step kt, only B(kt+1)'s 2 DMAs are
// outstanding (vmcnt(2) at each barrier); B(kt) landed; av issued BEFORE
// B(kt+2) so the A ds_write's implicit wait leaves B(kt+2) in flight.
// Epilogue = r12 (verified): logits from C-frags, softmax, kvT/wJ swizzled
// staging, PV MFMAs, cross-wave pair reduce, f16 stores to Pmid.
// ---------------------------------------------------------------------------
__global__ __launch_bounds__(256, 4) void k_gemm(const float* __restrict__ cp,
                                                 const unsigned short* __restrict__ Ft,
                                                 const float* __restrict__ q2g,
                                                 unsigned short* __restrict__ Pmid){
    __shared__ __align__(16) char smem[40960];
    unsigned short (*As)[4096] = (unsigned short (*)[4096])smem;            // 2 x 8 KB
    unsigned short (*Fs)[4096] = (unsigned short (*)[4096])(smem + 16384);  // 3 x 8 KB
    const int tid  = threadIdx.x;
    const int lane = tid & 63;
    const int wave = tid >> 6;              // 0..3
    const int wm = wave >> 1, wn2 = wave & 1;
    const int l15 = lane & 15, g = lane >> 4;
    const int mtile = blockIdx.x;           // 0..31
    const int n2 = blockIdx.y;              // 0..63
    const int n2h = n2 >> 4, y = n2 & 15;

    const float* abase[4];
    int aoff[4];
#pragma unroll
    for (int p = 0; p < 4; ++p){
        const int idx = tid + p * 256;      // 0..1023
        const int m = idx >> 3;             // 0..127
        const int kq = idx & 7;             // k = kq*4
        const int b = mtile * 8 + (m >> 4);
        const int i = (m & 15) * 4 + n2h;
        abase[p] = cp + (size_t)b * 262144 + (size_t)i * 4096 + (size_t)y * 256 + kq * 4;
        aoff[p] = m * 32 + (((kq >> 1) ^ ((m >> 1) & 3)) * 8) + (kq & 1) * 4;
    }
    const unsigned short* bsrc[2];
    unsigned short* bdst[2];                // wave-uniform LDS base (lane x16B auto)
#pragma unroll
    for (int p = 0; p < 2; ++p){
        const int idx = tid + p * 256;      // 0..511
        const int h = idx >> 2;             // 0..127
        const int kq4 = idx & 3;            // chunk of 8 f16
        bsrc[p] = Ft + (size_t)n2 * 32768 + (size_t)h * 256 + ((kq4 ^ ((h >> 1) & 3)) * 8);
        bdst[p] = &Fs[0][(size_t)(p * 256 + (tid & ~63)) * 8];
    }
    int afoff[4], bfoff[4];
#pragma unroll
    for (int mf = 0; mf < 4; ++mf){
        const int row = wm * 64 + mf * 16 + l15;
        afoff[mf] = row * 32 + ((g ^ ((row >> 1) & 3)) * 8);
    }
#pragma unroll
    for (int nf = 0; nf < 4; ++nf){
        const int row = wn2 * 64 + nf * 16 + l15;
        bfoff[nf] = row * 32 + ((g ^ ((row >> 1) & 3)) * 8);
    }

    f32x4 acc[4][4];
#pragma unroll
    for (int mf = 0; mf < 4; ++mf)
#pragma unroll
        for (int nf = 0; nf < 4; ++nf) acc[mf][nf] = (f32x4){0.f, 0.f, 0.f, 0.f};

    float4 av[4];
    // ---- prologue: B kt=0 -> buf0, B kt=1 -> buf1, A kt=0 -> As[0] ----
#pragma unroll
    for (int p = 0; p < 2; ++p) gload_lds16(bsrc[p], bdst[p]);
#pragma unroll
    for (int p = 0; p < 2; ++p) gload_lds16(bsrc[p] + 32, bdst[p] + 4096);
#pragma unroll
    for (int p = 0; p < 4; ++p) av[p] = *(const float4*)(abase[p]);
#pragma unroll
    for (int p = 0; p < 4; ++p){
        uint2 w2 = make_uint2(pk2h(av[p].x, av[p].y), pk2h(av[p].z, av[p].w));
        *(uint2*)(&As[0][aoff[p]]) = w2;
    }
    __syncthreads();   // one-time full drain (B0,B1 land here)

#pragma unroll
    for (int kt = 0; kt < 8; ++kt){
        // 1. issue A(kt+1) reg loads FIRST (older than B(kt+2) in vmcnt queue)
        if (kt < 7){
#pragma unroll
            for (int p = 0; p < 4; ++p) av[p] = *(const float4*)(abase[p] + (kt + 1) * 32);
        }
        __builtin_amdgcn_sched_barrier(0);   // keep av-issue before B-issue
        // 2. issue B(kt+2) DMAs into buf (kt+2)%3 (freed at barrier ending kt-1)
        if (kt < 6){
#pragma unroll
            for (int p = 0; p < 2; ++p)
                gload_lds16(bsrc[p] + (kt + 2) * 32, bdst[p] + ((kt + 2) % 3) * 4096);
        }
        // 3. compute from As[kt&1], Fs[kt%3] (B(kt) landed per invariant)
        f16x8 af[4], bfr[4];
#pragma unroll
        for (int mf = 0; mf < 4; ++mf) af[mf] = *(const f16x8*)(&As[kt & 1][afoff[mf]]);
#pragma unroll
        for (int nf = 0; nf < 4; ++nf) bfr[nf] = *(const f16x8*)(&Fs[kt % 3][bfoff[nf]]);
#pragma unroll
        for (int nf = 0; nf < 4; ++nf)
#pragma unroll
            for (int mf = 0; mf < 4; ++mf)
                acc[mf][nf] = __builtin_amdgcn_mfma_f32_16x16x32_f16(af[mf], bfr[nf], acc[mf][nf], 0, 0, 0);
        // 4. convert + write A(kt+1); implicit wait = vmcnt(2), leaves B(kt+2) in flight
        if (kt < 7){
#pragma unroll
            for (int p = 0; p < 4; ++p){
                uint2 w2 = make_uint2(pk2h(av[p].x, av[p].y), pk2h(av[p].z, av[p].w));
                *(uint2*)(&As[(kt + 1) & 1][aoff[p]]) = w2;
            }
        }
        // 5. fence: B(kt+1) landed (only B(kt+2) may remain) + DS writes visible
        if (kt < 6){ asm volatile("s_waitcnt vmcnt(2) lgkmcnt(0)" ::: "memory"); }
        else       { asm volatile("s_waitcnt vmcnt(0) lgkmcnt(0)" ::: "memory"); }
        __builtin_amdgcn_s_barrier();
        __builtin_amdgcn_sched_barrier(0);
    }
    // Past the last barrier: all LDS traffic retired; epilogue aliases smem.

    char* eb  = smem + wave * 6144;
    char* kvT = eb;            // [16 e][128 B] col n*2 ^ ((e&7)<<4)
    char* wJ  = eb + 2048;     // [32 j][128 B] col n*2 ^ ((j&7)<<4)
    const f32x4 zf = (f32x4){0.f, 0.f, 0.f, 0.f};
    f32x4 pvm[4][2];

#pragma unroll
    for (int mf = 0; mf < 4; ++mf){
        const int b = mtile * 8 + wm * 4 + mf;
        U4H8 aq[2];
#pragma unroll
        for (int jh = 0; jh < 2; ++jh){
            const float4 q = *(const float4*)(q2g + (size_t)b * 512
                                              + (size_t)(jh * 16 + l15) * 16 + g * 4);
            aq[jh].u = make_uint4(pk2h(q.x, q.y), pk2h(q.z, q.w), 0u, 0u);
        }
        f32x4 pv0 = zf, pv1 = zf;
#pragma unroll
        for (int nf = 0; nf < 4; ++nf){
            U4H8 B;
            B.u = make_uint4(pk2h(acc[mf][nf][0], acc[mf][nf][1]),
                             pk2h(acc[mf][nf][2], acc[mf][nf][3]), 0u, 0u);
            const int ncol2 = (nf * 16 + l15) * 2;
#pragma unroll
            for (int r = 0; r < 4; ++r){
                const int e = g * 4 + r;
                *(unsigned short*)(kvT + e * 128 + (ncol2 ^ ((e & 7) << 4))) = B.s[r];
            }
            f32x4 s0 = __builtin_amdgcn_mfma_f32_16x16x32_f16(aq[0].v, B.v, zf, 0, 0, 0);
            f32x4 s1 = __builtin_amdgcn_mfma_f32_16x16x32_f16(aq[1].v, B.v, zf, 0, 0, 0);
            float e0[4], e1[4];
#pragma unroll
            for (int r = 0; r < 4; ++r){ e0[r] = __expf(s0[r]); e1[r] = __expf(s1[r]); }
            float ts = ((e0[0] + e0[1]) + (e0[2] + e0[3]))
                     + ((e1[0] + e1[1]) + (e1[2] + e1[3]));
            ts += __shfl_xor(ts, 16);
            ts += __shfl_xor(ts, 32);
            const float dinv = 1.f / ts;
#pragma unroll
            for (int r = 0; r < 4; ++r){
                const int j0 = 4 * g + r;
                const int sw = (j0 & 7) << 4;
                *(unsigned short*)(wJ + j0 * 128 + (ncol2 ^ sw)) =
                    (unsigned short)(pk2h(e0[r] * dinv, 0.f) & 0xFFFFu);
                *(unsigned short*)(wJ + (16 + j0) * 128 + (ncol2 ^ sw)) =
                    (unsigned short)(pk2h(e1[r] * dinv, 0.f) & 0xFFFFu);
            }
        }
#pragma unroll
        for (int kb = 0; kb < 2; ++kb){
            const int cb = kb * 64 + g * 16;
            const int swl = (l15 & 7) << 4;
            U4H8 A0, A1, Bv;
            A0.u = *(const uint4*)(wJ + l15 * 128 + (cb ^ swl));
            A1.u = *(const uint4*)(wJ + (16 + l15) * 128 + (cb ^ swl));
            Bv.u = *(const uint4*)(kvT + l15 * 128 + (cb ^ swl));
            pv0 = __builtin_amdgcn_mfma_f32_16x16x32_f16(A0.v, Bv.v, pv0, 0, 0, 0);
            pv1 = __builtin_amdgcn_mfma_f32_16x16x32_f16(A1.v, Bv.v, pv1, 0, 0, 0);
        }
        pvm[mf][0] = pv0;
        pvm[mf][1] = pv1;
    }

    // ---- cross-wave pair reduce, then f16 store to Pmid ----
    __syncthreads();
    float* pvbuf = (float*)(smem + wm * 8192);   // [4 mf][32 j][16 e] f32
    if (wn2 == 0){
#pragma unroll
        for (int mf = 0; mf < 4; ++mf)
#pragma unroll
            for (int jh = 0; jh < 2; ++jh)
#pragma unroll
                for (int r = 0; r < 4; ++r)
                    pvbuf[mf * 512 + (jh * 16 + 4 * g + r) * 16 + l15] = pvm[mf][jh][r];
    }
    __syncthreads();
    if (wn2 == 1){
#pragma unroll
        for (int mf = 0; mf < 4; ++mf){
            const int b = mtile * 8 + wm * 4 + mf;
            unsigned short* dst = Pmid + (size_t)n2 * 131072 + (size_t)b * 512;
#pragma unroll
            for (int jh = 0; jh < 2; ++jh)
#pragma unroll
                for (int r = 0; r < 4; ++r){
                    const int idx = (jh * 16 + 4 * g + r) * 16 + l15;
                    const float sum = pvbuf[mf * 512 + idx] + pvm[mf][jh][r];
                    dst[idx] = (unsigned short)(pk2h(sum, 0.f) & 0xFFFFu);
                }
        }
    }
}

// ---------------------------------------------------------------------------
// Kernel 3: sum 64 f16 n2-slices, w_next transform, LayerNorm, store.
// 256 threads: thread owns 2 consecutive elements (one u32 of 2 f16).
// ---------------------------------------------------------------------------
__global__ __launch_bounds__(256) void k_fin(const unsigned* __restrict__ Pmid,
                                             const float* __restrict__ wn,
                                             const float* __restrict__ lnw,
                                             const float* __restrict__ lnb,
                                             float* __restrict__ out){
    __shared__ float cnd[512];
    const int b = blockIdx.x, t = threadIdx.x;
    float s0 = 0.f, s1 = 0.f;
#pragma unroll 8
    for (int n2 = 0; n2 < 64; ++n2){
        U1H2 c; c.u = Pmid[(size_t)n2 * 65536 + (size_t)b * 256 + t];
        s0 += (float)c.h[0];
        s1 += (float)c.h[1];
    }
    cnd[2 * t]     = s0;
    cnd[2 * t + 1] = s1;
    __syncthreads();
    if (t < 32){
        const int o = t;
        float m2[16];
#pragma unroll
        for (int r = 0; r < 4; ++r)
#pragma unroll
            for (int c = 0; c < 4; ++c){
                float a = 0.f;
#pragma unroll
                for (int k = 0; k < 4; ++k)
                    a += wn[o * 16 + r * 4 + k] * cnd[o * 16 + k * 4 + c];
                m2[r * 4 + c] = a;
            }
        float mu = 0.f;
#pragma unroll
        for (int e = 0; e < 16; ++e) mu += m2[e];
        mu *= (1.f / 16.f);
        float var = 0.f;
#pragma unroll
        for (int e = 0; e < 16; ++e){ const float d = m2[e] - mu; var += d * d; }
        var *= (1.f / 16.f);
        const float invs = rsqrtf(var + EPSF);
#pragma unroll
        for (int e = 0; e < 16; ++e)
            out[(size_t)b * 512 + o * 16 + e] = (m2[e] - mu) * invs * lnw[e] + lnb[e];
    }
}

// ---------------------------------------------------------------------------
extern "C" void kernel_launch(void* const* d_in, const int* in_sizes, int n_in,
                              void* d_out, int out_size, void* d_ws, size_t ws_size,
                              hipStream_t stream){
    const float* cp   = (const float*)d_in[0];   // current_pose [256][64][16][16][16]
    const float* npse = (const float*)d_in[1];   // next_pose    [256][32][16]
    const float* wc   = (const float*)d_in[2];   // w_current    [64][4][4]
    const float* wn   = (const float*)d_in[3];   // w_next       [32][4][4]
    const float* E    = (const float*)d_in[4];   // E_proj       [64][256][128]
    const float* lnw  = (const float*)d_in[5];   // ln_weight    [16]
    const float* lnb  = (const float*)d_in[6];   // ln_bias      [16]
    float* out = (float*)d_out;

    char* ws = (char*)d_ws;
    unsigned short* Ft   = (unsigned short*)ws;                // 4,194,304 B
    float*          q2g  = (float*)(ws + 4194304);             // 524,288 B
    unsigned short* Pmid = (unsigned short*)(ws + 4718592);    // 16,777,216 B

    hipLaunchKernelGGL(k_init, dim3(1280), dim3(128), 0, stream, wc, E, npse, wn, Ft, q2g);
    hipLaunchKernelGGL(k_gemm, dim3(32, 64), dim3(256), 0, stream, cp, Ft, q2g, Pmid);
    hipLaunchKernelGGL(k_fin,  dim3(256), dim3(256), 0, stream, (const unsigned*)Pmid, wn, lnw, lnb, out);
}